// Round 11
// baseline (620.567 us; speedup 1.0000x reference)
//
#include <hip/hip_runtime.h>
#include <hip/hip_bf16.h>
#include <cstdint>
#include <cstddef>
#include <math.h>

#define NEG_SLOPE 0.2f

__device__ __forceinline__ float lrelu(float x) { return x > 0.f ? x : NEG_SLOPE * x; }

// Layouts (r6/r10-proven):
//  xw  slice-major [8][N][16]. r11: slice is chosen by the block's PHYSICAL XCD
//      (s_getreg HW_REG_XCC_ID) + per-slice work queue — r10 showed the blockIdx%8
//      heuristic drifts with long-running blocks (FETCH 70->414 MB).
//  pk  head-major planes [4][Et] packed {src:int, e:float}; e precomputed in
//      scatter (r7: on-the-fly recompute regressed).
//  k_agg: 4 lanes/dst x 16 dsts/wave (r10: removed issue bound).
//  Cooperative single-kernel fusion DISPROVEN (r9: grid.sync L2-drain, 1343 us).

// ================= K1: GEMM (blocks < GB) UNION degree-count (blocks >= GB) ======
__global__ __launch_bounds__(256) void k_gemm_count(
    const float* __restrict__ x, const float* __restrict__ W1,
    const float* __restrict__ att_src, const float* __restrict__ att_dst,
    const int* __restrict__ ei, int E, int N, int GB,
    float* __restrict__ xw, float* __restrict__ a_src, float* __restrict__ a_dst,
    int* __restrict__ deg)
{
    __shared__ float As[32 * 68];
    __shared__ float Bs[32 * 132];

    if (blockIdx.x >= GB) {                    // ---- count blocks (overlap with GEMM)
        const int Et = E + N;
        const int stride = (gridDim.x - GB) * 256;
        for (int e = (blockIdx.x - GB) * 256 + threadIdx.x; e < Et; e += stride) {
            int d = (e < E) ? ei[(size_t)E + e] : (e - E);
            atomicAdd(&deg[d], 1);
        }
        return;
    }

    const int tid = threadIdx.x;
    const int tx = tid & 31, ty = tid >> 5;
    const int bm = blockIdx.x * 64;
    float acc[8][4] = {};

    for (int k0 = 0; k0 < 128; k0 += 32) {
        #pragma unroll
        for (int t = tid; t < 512; t += 256) {
            int r = t >> 3, q = t & 7;
            int n = bm + r;
            float4 f = make_float4(0.f, 0.f, 0.f, 0.f);
            if (n < N) f = *(const float4*)(x + (size_t)n * 128 + k0 + 4 * q);
            As[(4*q+0)*68 + r] = f.x; As[(4*q+1)*68 + r] = f.y;
            As[(4*q+2)*68 + r] = f.z; As[(4*q+3)*68 + r] = f.w;
        }
        #pragma unroll
        for (int t = tid; t < 1024; t += 256) {
            int c = t >> 3, q = t & 7;
            float4 f = *(const float4*)(W1 + (size_t)c * 128 + k0 + 4 * q);
            Bs[(4*q+0)*132 + c] = f.x; Bs[(4*q+1)*132 + c] = f.y;
            Bs[(4*q+2)*132 + c] = f.z; Bs[(4*q+3)*132 + c] = f.w;
        }
        __syncthreads();
        #pragma unroll 8
        for (int kk = 0; kk < 32; kk++) {
            float4 a0 = *(const float4*)&As[kk * 68 + ty * 8];
            float4 a1 = *(const float4*)&As[kk * 68 + ty * 8 + 4];
            float4 b4 = *(const float4*)&Bs[kk * 132 + tx * 4];
            float a[8] = {a0.x, a0.y, a0.z, a0.w, a1.x, a1.y, a1.z, a1.w};
            float b[4] = {b4.x, b4.y, b4.z, b4.w};
            #pragma unroll
            for (int i = 0; i < 8; i++)
                #pragma unroll
                for (int j = 0; j < 4; j++) acc[i][j] = fmaf(a[i], b[j], acc[i][j]);
        }
        __syncthreads();
    }

    float asv[4], adv[4];
    #pragma unroll
    for (int j = 0; j < 4; j++) { asv[j] = att_src[tx*4+j]; adv[j] = att_dst[tx*4+j]; }
    const int slice = tx >> 2, cio = (tx & 3) * 4, head = tx >> 3;

    #pragma unroll
    for (int i = 0; i < 8; i++) {
        int n = bm + ty * 8 + i;
        float sv = 0.f, dv = 0.f;
        #pragma unroll
        for (int j = 0; j < 4; j++) {
            sv = fmaf(acc[i][j], asv[j], sv);
            dv = fmaf(acc[i][j], adv[j], dv);
        }
        #pragma unroll
        for (int off = 1; off < 8; off <<= 1) {   // 8 lanes of one head
            sv += __shfl_xor(sv, off);
            dv += __shfl_xor(dv, off);
        }
        if (n < N) {
            *(float4*)&xw[((size_t)slice * N + n) * 16 + cio] =
                make_float4(acc[i][0], acc[i][1], acc[i][2], acc[i][3]);
            if ((tx & 7) == 0) {
                a_src[n * 4 + head] = sv;
                a_dst[n * 4 + head] = dv;
            }
        }
    }
}

// ================= K2: single-pass decoupled-lookback scan; zeroes xw2 ===========
__global__ __launch_bounds__(256) void k_scan_lb(const int* __restrict__ deg,
                                                 int* __restrict__ row_ptr,
                                                 int* __restrict__ cursor,
                                                 float* __restrict__ xw2,
                                                 unsigned* __restrict__ post,
                                                 int N, int nblk)
{
    __shared__ int sw[4];
    __shared__ int s_excl;
    const int b = blockIdx.x, tid = threadIdx.x, wv = tid >> 6, lane = tid & 63;
    const int base = b * 2048 + tid * 8;

    int v[8];
    #pragma unroll
    for (int i = 0; i < 8; i++) v[i] = (base + i < N) ? deg[base + i] : 0;
    int tsum = 0;
    #pragma unroll
    for (int i = 0; i < 8; i++) tsum += v[i];

    int inc = tsum;
    #pragma unroll
    for (int off = 1; off < 64; off <<= 1) {
        int u = __shfl_up(inc, off);
        if (lane >= off) inc += u;
    }
    if (lane == 63) sw[wv] = inc;
    __syncthreads();
    int woff = 0;
    for (int i = 0; i < wv; i++) woff += sw[i];
    const int thr_excl = woff + inc - tsum;
    const int total = sw[0] + sw[1] + sw[2] + sw[3];

    if (tid == 0) {
        int excl = 0;
        if (b == 0) {
            __hip_atomic_store(&post[0], ((unsigned)total << 2) | 2u,
                               __ATOMIC_RELEASE, __HIP_MEMORY_SCOPE_AGENT);
        } else {
            __hip_atomic_store(&post[b], ((unsigned)total << 2) | 1u,
                               __ATOMIC_RELEASE, __HIP_MEMORY_SCOPE_AGENT);
            int j = b - 1;
            long long sum = 0;
            while (true) {
                unsigned pv = __hip_atomic_load(&post[j], __ATOMIC_ACQUIRE,
                                                __HIP_MEMORY_SCOPE_AGENT);
                unsigned st = pv & 3u;
                if (st == 0u) { __builtin_amdgcn_s_sleep(1); continue; }
                sum += (pv >> 2);
                if (st == 2u) break;
                j--;
            }
            excl = (int)sum;
            __hip_atomic_store(&post[b], ((unsigned)(excl + total) << 2) | 2u,
                               __ATOMIC_RELEASE, __HIP_MEMORY_SCOPE_AGENT);
        }
        s_excl = excl;
        if (b == nblk - 1) row_ptr[N] = excl + total;
    }
    __syncthreads();

    int run = s_excl + thr_excl;
    #pragma unroll
    for (int i = 0; i < 8; i++) {
        int idx = base + i;
        if (idx < N) {
            row_ptr[idx] = run;
            cursor[idx]  = run;
            xw2[idx]     = 0.f;
            run += v[i];
        }
    }
}

// ================= K3: scatter + packed unnormalized softmax weights ==============
__global__ void k_scatter(const int* __restrict__ ei, int E, int N,
                          int* __restrict__ cursor,
                          const float* __restrict__ a_src,
                          const float* __restrict__ a_dst,
                          uint2* __restrict__ pk, int Et)
{
    int e = blockIdx.x * blockDim.x + threadIdx.x;
    if (e >= Et) return;
    int s, d;
    if (e < E) { s = ei[e]; d = ei[(size_t)E + e]; }
    else       { s = d = e - E; }
    int pos = atomicAdd(&cursor[d], 1);
    float4 as4 = ((const float4*)a_src)[s];
    float4 ad4 = ((const float4*)a_dst)[d];
    unsigned us = (unsigned)s;
    pk[(size_t)0 * Et + pos] = make_uint2(us, __float_as_uint(__expf(lrelu(as4.x + ad4.x))));
    pk[(size_t)1 * Et + pos] = make_uint2(us, __float_as_uint(__expf(lrelu(as4.y + ad4.y))));
    pk[(size_t)2 * Et + pos] = make_uint2(us, __float_as_uint(__expf(lrelu(as4.z + ad4.z))));
    pk[(size_t)3 * Et + pos] = make_uint2(us, __float_as_uint(__expf(lrelu(as4.w + ad4.w))));
}

// ================= K4: agg — XCD-exact slice binding + per-slice work queues ======
// Block reads its physical XCD (HW_REG_XCC_ID) -> processes that slice; grabs
// 64-dst chunks from qnext[slice]. Tail: steal from other slices (correctness
// never depends on dispatch placement; queues are grab-only, no waiting).
// Inner: 4 lanes/dst x 16 dsts/wave (r10).
__global__ __launch_bounds__(256) void k_agg(const float* __restrict__ xw,
                                             const uint2* __restrict__ pk,
                                             const int* __restrict__ row_ptr,
                                             const float* __restrict__ b1,
                                             const float* __restrict__ W2,
                                             float* __restrict__ xw2,
                                             int* __restrict__ qnext,
                                             int N, int Et)
{
    const int tid = threadIdx.x;
    const int wv = tid >> 6, lane = tid & 63;
    const int grp = lane >> 2, li = lane & 3;     // 16 dst-groups x 4 ch-lanes
    const int nchunk = (N + 63) >> 6;
    __shared__ int s_xcd, s_chunk;

    if (tid == 0) {
        unsigned xcc;
        asm volatile("s_getreg_b32 %0, hwreg(HW_REG_XCC_ID)" : "=s"(xcc));
        s_xcd = (int)(xcc & 7u);
    }
    __syncthreads();
    const int myxcd = s_xcd;

    for (int sof = 0; sof < 8; sof++) {           // own slice first, then steal
        const int slice = (myxcd + sof) & 7;
        const float4* xs4 = (const float4*)(xw + (size_t)slice * N * 16);
        const uint2*  ph  = pk + (size_t)(slice >> 1) * Et;
        const float4  bb  = ((const float4*)b1)[slice * 4 + li];
        const float4  ww  = ((const float4*)W2)[slice * 4 + li];
        while (true) {
            __syncthreads();
            if (tid == 0) s_chunk = atomicAdd(&qnext[slice], 1);
            __syncthreads();
            const int c = s_chunk;
            if (c >= nchunk) break;
            const int d = c * 64 + wv * 16 + grp;
            if (d < N) {
                const int beg = row_ptr[d], end = row_ptr[d + 1];
                float4 acc = make_float4(0.f, 0.f, 0.f, 0.f);
                float csum = 0.f;
                for (int k = beg; k < end; ++k) {
                    uint2 p = ph[k];
                    float cc = __uint_as_float(p.y);
                    float4 v = xs4[(size_t)p.x * 4 + li];
                    acc.x = fmaf(cc, v.x, acc.x);
                    acc.y = fmaf(cc, v.y, acc.y);
                    acc.z = fmaf(cc, v.z, acc.z);
                    acc.w = fmaf(cc, v.w, acc.w);
                    csum += cc;
                }
                float inv = 1.f / (csum + 1e-16f);
                float t = fmaxf(fmaf(acc.x, inv, bb.x), 0.f) * ww.x
                        + fmaxf(fmaf(acc.y, inv, bb.y), 0.f) * ww.y
                        + fmaxf(fmaf(acc.z, inv, bb.z), 0.f) * ww.z
                        + fmaxf(fmaf(acc.w, inv, bb.w), 0.f) * ww.w;
                t += __shfl_xor(t, 1);
                t += __shfl_xor(t, 2);
                if (li == 0) atomicAdd(&xw2[d], t);
            }
        }
    }
}

// ================= K5: layer 2 — scalar GAT head, 4 dsts/wave x 16 lanes ==========
__global__ __launch_bounds__(256) void k_layer2(const float* __restrict__ xw2,
                                                const int* __restrict__ row_ptr,
                                                const uint2* __restrict__ pk0,
                                                const float* __restrict__ att_src2,
                                                const float* __restrict__ att_dst2,
                                                const float* __restrict__ b2,
                                                float* __restrict__ out, int N)
{
    int grpi = (blockIdx.x * blockDim.x + threadIdx.x) >> 6;
    int lane = threadIdx.x & 63;
    int sub  = lane >> 4, li = lane & 15;
    int d    = grpi * 4 + sub;
    if (d >= N) return;
    float as2  = att_src2[0];
    float adst = xw2[d] * att_dst2[0];
    float l = 0.f, acc = 0.f;
    int beg = row_ptr[d], end = row_ptr[d + 1];
    for (int j = beg + li; j < end; j += 16) {
        int s = (int)pk0[j].x;
        float xs = xw2[s];
        float p = __expf(lrelu(fmaf(xs, as2, adst)));
        l += p;
        acc = fmaf(p, xs, acc);
    }
    #pragma unroll
    for (int off = 1; off < 16; off <<= 1) {
        l   += __shfl_xor(l, off);
        acc += __shfl_xor(acc, off);
    }
    if (li == 0) out[d] = acc / (l + 1e-16f) + b2[0];
}

extern "C" void kernel_launch(void* const* d_in, const int* in_sizes, int n_in,
                              void* d_out, int out_size, void* d_ws, size_t ws_size,
                              hipStream_t stream)
{
    const float* x        = (const float*)d_in[0];
    const int*   ei       = (const int*)d_in[1];
    const float* W1       = (const float*)d_in[2];
    const float* att_src1 = (const float*)d_in[3];
    const float* att_dst1 = (const float*)d_in[4];
    const float* b1       = (const float*)d_in[5];
    const float* W2       = (const float*)d_in[6];
    const float* att_src2 = (const float*)d_in[7];
    const float* att_dst2 = (const float*)d_in[8];
    const float* b2       = (const float*)d_in[9];
    float* out = (float*)d_out;

    const int N  = in_sizes[0] / 128;
    const int E  = in_sizes[1] / 2;
    const int Et = E + N;
    const int nblk = (N + 2047) / 2048;        // lookback-scan blocks (25 for N=50k)

    char* p = (char*)d_ws;
    auto alloc = [&](size_t bytes) {
        char* r = p;
        p += (bytes + 255) & ~(size_t)255;
        return (void*)r;
    };
    float*    xw      = (float*)alloc((size_t)N * 128 * 4);  // slice-major [8][N][16]
    float*    a_src   = (float*)alloc((size_t)N * 4 * 4);
    float*    a_dst   = (float*)alloc((size_t)N * 4 * 4);
    float*    xw2     = (float*)alloc((size_t)N * 4);
    int*      degpost = (int*)alloc((size_t)(N + nblk + 16) * 4); // deg+post+qnext
    int*      deg     = degpost;
    unsigned* post    = (unsigned*)(degpost + N);
    int*      qnext   = degpost + N + nblk;
    int*      row_ptr = (int*)alloc((size_t)(N + 1) * 4);
    int*      cursor  = (int*)alloc((size_t)N * 4);
    uint2*    pk      = (uint2*)alloc((size_t)4 * Et * 8);   // [4][Et] packed {s, e_h}

    hipMemsetAsync(degpost, 0, (size_t)(N + nblk + 16) * 4, stream);

    const int GB = (N + 63) / 64;
    k_gemm_count<<<GB + 256, 256, 0, stream>>>(x, W1, att_src1, att_dst1, ei, E, N, GB,
                                               xw, a_src, a_dst, deg);
    k_scan_lb  <<<nblk,           256, 0, stream>>>(deg, row_ptr, cursor, xw2, post,
                                                    N, nblk);
    k_scatter  <<<(Et + 255)/256, 256, 0, stream>>>(ei, E, N, cursor, a_src, a_dst,
                                                    pk, Et);
    k_agg      <<<2048,           256, 0, stream>>>(xw, pk, row_ptr, b1, W2, xw2,
                                                    qnext, N, Et);
    k_layer2   <<<(N + 15)/16,    256, 0, stream>>>(xw2, row_ptr, pk, att_src2,
                                                    att_dst2, b2, out, N);
}

// Round 12
// 534.966 us; speedup vs baseline: 1.1600x; 1.1600x over previous
//
#include <hip/hip_runtime.h>
#include <hip/hip_bf16.h>
#include <cstdint>
#include <cstddef>
#include <math.h>

#define NEG_SLOPE 0.2f

__device__ __forceinline__ float lrelu(float x) { return x > 0.f ? x : NEG_SLOPE * x; }

// Layouts:
//  xw  slice-major [8][N][16]; pk head-major planes [4][Et] {src, e_h}.
//  r12 findings ledger:
//   - k_agg MUST be 1 dst/wave, 16 consecutive edge-slots (r6 shape): consecutive
//     pk reads -> lines fully consumed; 16-dst/wave (r10/r11) opens 16 scattered
//     pk streams/wave and thrashes L2 (FETCH 70->414 MB). XCD pinning irrelevant
//     (r11 refuted: exact HW XCC_ID binding didn't lower FETCH).
//   - pk scatter-writes are write-allocate-amplified: scatter only inv[pos]=e
//     (4B), build pk planes with COALESCED writes (k_build).
//   - cooperative fusion disproven (r9); on-the-fly e recompute disproven (r7).

// ================= K1: GEMM (blocks < GB) UNION degree-count (blocks >= GB) ======
__global__ __launch_bounds__(256) void k_gemm_count(
    const float* __restrict__ x, const float* __restrict__ W1,
    const float* __restrict__ att_src, const float* __restrict__ att_dst,
    const int* __restrict__ ei, int E, int N, int GB,
    float* __restrict__ xw, float* __restrict__ a_src, float* __restrict__ a_dst,
    int* __restrict__ deg)
{
    __shared__ float As[32 * 68];
    __shared__ float Bs[32 * 132];

    if (blockIdx.x >= GB) {                    // ---- count blocks (overlap with GEMM)
        const int Et = E + N;
        const int stride = (gridDim.x - GB) * 256;
        for (int e = (blockIdx.x - GB) * 256 + threadIdx.x; e < Et; e += stride) {
            int d = (e < E) ? ei[(size_t)E + e] : (e - E);
            atomicAdd(&deg[d], 1);
        }
        return;
    }

    const int tid = threadIdx.x;
    const int tx = tid & 31, ty = tid >> 5;
    const int bm = blockIdx.x * 64;
    float acc[8][4] = {};

    for (int k0 = 0; k0 < 128; k0 += 32) {
        #pragma unroll
        for (int t = tid; t < 512; t += 256) {
            int r = t >> 3, q = t & 7;
            int n = bm + r;
            float4 f = make_float4(0.f, 0.f, 0.f, 0.f);
            if (n < N) f = *(const float4*)(x + (size_t)n * 128 + k0 + 4 * q);
            As[(4*q+0)*68 + r] = f.x; As[(4*q+1)*68 + r] = f.y;
            As[(4*q+2)*68 + r] = f.z; As[(4*q+3)*68 + r] = f.w;
        }
        #pragma unroll
        for (int t = tid; t < 1024; t += 256) {
            int c = t >> 3, q = t & 7;
            float4 f = *(const float4*)(W1 + (size_t)c * 128 + k0 + 4 * q);
            Bs[(4*q+0)*132 + c] = f.x; Bs[(4*q+1)*132 + c] = f.y;
            Bs[(4*q+2)*132 + c] = f.z; Bs[(4*q+3)*132 + c] = f.w;
        }
        __syncthreads();
        #pragma unroll 8
        for (int kk = 0; kk < 32; kk++) {
            float4 a0 = *(const float4*)&As[kk * 68 + ty * 8];
            float4 a1 = *(const float4*)&As[kk * 68 + ty * 8 + 4];
            float4 b4 = *(const float4*)&Bs[kk * 132 + tx * 4];
            float a[8] = {a0.x, a0.y, a0.z, a0.w, a1.x, a1.y, a1.z, a1.w};
            float b[4] = {b4.x, b4.y, b4.z, b4.w};
            #pragma unroll
            for (int i = 0; i < 8; i++)
                #pragma unroll
                for (int j = 0; j < 4; j++) acc[i][j] = fmaf(a[i], b[j], acc[i][j]);
        }
        __syncthreads();
    }

    float asv[4], adv[4];
    #pragma unroll
    for (int j = 0; j < 4; j++) { asv[j] = att_src[tx*4+j]; adv[j] = att_dst[tx*4+j]; }
    const int slice = tx >> 2, cio = (tx & 3) * 4, head = tx >> 3;

    #pragma unroll
    for (int i = 0; i < 8; i++) {
        int n = bm + ty * 8 + i;
        float sv = 0.f, dv = 0.f;
        #pragma unroll
        for (int j = 0; j < 4; j++) {
            sv = fmaf(acc[i][j], asv[j], sv);
            dv = fmaf(acc[i][j], adv[j], dv);
        }
        #pragma unroll
        for (int off = 1; off < 8; off <<= 1) {   // 8 lanes of one head
            sv += __shfl_xor(sv, off);
            dv += __shfl_xor(dv, off);
        }
        if (n < N) {
            *(float4*)&xw[((size_t)slice * N + n) * 16 + cio] =
                make_float4(acc[i][0], acc[i][1], acc[i][2], acc[i][3]);
            if ((tx & 7) == 0) {
                a_src[n * 4 + head] = sv;
                a_dst[n * 4 + head] = dv;
            }
        }
    }
}

// ================= K2: single-pass decoupled-lookback scan; zeroes xw2 ===========
__global__ __launch_bounds__(256) void k_scan_lb(const int* __restrict__ deg,
                                                 int* __restrict__ row_ptr,
                                                 int* __restrict__ cursor,
                                                 float* __restrict__ xw2,
                                                 unsigned* __restrict__ post,
                                                 int N, int nblk)
{
    __shared__ int sw[4];
    __shared__ int s_excl;
    const int b = blockIdx.x, tid = threadIdx.x, wv = tid >> 6, lane = tid & 63;
    const int base = b * 2048 + tid * 8;

    int v[8];
    #pragma unroll
    for (int i = 0; i < 8; i++) v[i] = (base + i < N) ? deg[base + i] : 0;
    int tsum = 0;
    #pragma unroll
    for (int i = 0; i < 8; i++) tsum += v[i];

    int inc = tsum;
    #pragma unroll
    for (int off = 1; off < 64; off <<= 1) {
        int u = __shfl_up(inc, off);
        if (lane >= off) inc += u;
    }
    if (lane == 63) sw[wv] = inc;
    __syncthreads();
    int woff = 0;
    for (int i = 0; i < wv; i++) woff += sw[i];
    const int thr_excl = woff + inc - tsum;
    const int total = sw[0] + sw[1] + sw[2] + sw[3];

    if (tid == 0) {
        int excl = 0;
        if (b == 0) {
            __hip_atomic_store(&post[0], ((unsigned)total << 2) | 2u,
                               __ATOMIC_RELEASE, __HIP_MEMORY_SCOPE_AGENT);
        } else {
            __hip_atomic_store(&post[b], ((unsigned)total << 2) | 1u,
                               __ATOMIC_RELEASE, __HIP_MEMORY_SCOPE_AGENT);
            int j = b - 1;
            long long sum = 0;
            while (true) {
                unsigned pv = __hip_atomic_load(&post[j], __ATOMIC_ACQUIRE,
                                                __HIP_MEMORY_SCOPE_AGENT);
                unsigned st = pv & 3u;
                if (st == 0u) { __builtin_amdgcn_s_sleep(1); continue; }
                sum += (pv >> 2);
                if (st == 2u) break;
                j--;
            }
            excl = (int)sum;
            __hip_atomic_store(&post[b], ((unsigned)(excl + total) << 2) | 2u,
                               __ATOMIC_RELEASE, __HIP_MEMORY_SCOPE_AGENT);
        }
        s_excl = excl;
        if (b == nblk - 1) row_ptr[N] = excl + total;
    }
    __syncthreads();

    int run = s_excl + thr_excl;
    #pragma unroll
    for (int i = 0; i < 8; i++) {
        int idx = base + i;
        if (idx < N) {
            row_ptr[idx] = run;
            cursor[idx]  = run;
            xw2[idx]     = 0.f;
            run += v[i];
        }
    }
}

// ================= K3a: position scatter (4B writes only) =========================
__global__ void k_scatter_pos(const int* __restrict__ ei, int E, int N,
                              int* __restrict__ cursor, unsigned* __restrict__ inv,
                              int Et)
{
    int e = blockIdx.x * blockDim.x + threadIdx.x;
    if (e >= Et) return;
    int d = (e < E) ? ei[(size_t)E + e] : (e - E);
    int pos = atomicAdd(&cursor[d], 1);
    inv[pos] = (unsigned)e;
}

// ================= K3b: build pk planes with COALESCED writes =====================
__global__ void k_build(const int* __restrict__ ei, int E, int N,
                        const unsigned* __restrict__ inv,
                        const float* __restrict__ a_src,
                        const float* __restrict__ a_dst,
                        uint2* __restrict__ pk, int Et)
{
    int j = blockIdx.x * blockDim.x + threadIdx.x;
    if (j >= Et) return;
    int e = (int)inv[j];
    int s, d;
    if (e < E) { s = ei[e]; d = ei[(size_t)E + e]; }
    else       { s = d = e - E; }
    float4 as4 = ((const float4*)a_src)[s];
    float4 ad4 = ((const float4*)a_dst)[d];
    unsigned us = (unsigned)s;
    pk[(size_t)0 * Et + j] = make_uint2(us, __float_as_uint(__expf(lrelu(as4.x + ad4.x))));
    pk[(size_t)1 * Et + j] = make_uint2(us, __float_as_uint(__expf(lrelu(as4.y + ad4.y))));
    pk[(size_t)2 * Et + j] = make_uint2(us, __float_as_uint(__expf(lrelu(as4.z + ad4.z))));
    pk[(size_t)3 * Et + j] = make_uint2(us, __float_as_uint(__expf(lrelu(as4.w + ad4.w))));
}

// ================= K4: agg — r6 shape: 1 dst/wave, 16 slots x 4 ch-lanes =========
__global__ __launch_bounds__(256) void k_agg(const float* __restrict__ xw,
                                             const uint2* __restrict__ pk,
                                             const int* __restrict__ row_ptr,
                                             const float* __restrict__ b1,
                                             const float* __restrict__ W2,
                                             float* __restrict__ xw2, int N, int Et)
{
    const int slice = blockIdx.x & 7;
    const int dgrp  = blockIdx.x >> 3;
    const int wave  = threadIdx.x >> 6;
    const int lane  = threadIdx.x & 63;
    const int slot  = lane >> 2, li = lane & 3;       // 16 edge-slots x 4 ch-lanes
    const int d     = dgrp * 4 + wave;
    if (d >= N) return;
    const float4* xs4 = (const float4*)(xw + (size_t)slice * N * 16);
    const uint2*  ph  = pk + (size_t)(slice >> 1) * Et;

    const int beg = row_ptr[d];
    const int deg = row_ptr[d + 1] - beg;
    float4 acc = make_float4(0.f, 0.f, 0.f, 0.f);
    float csum = 0.f;
    #pragma unroll 2
    for (int k = slot; k < deg; k += 16) {
        uint2 p = ph[beg + k];
        float c = __uint_as_float(p.y);
        float4 v = xs4[(size_t)p.x * 4 + li];
        acc.x = fmaf(c, v.x, acc.x);
        acc.y = fmaf(c, v.y, acc.y);
        acc.z = fmaf(c, v.z, acc.z);
        acc.w = fmaf(c, v.w, acc.w);
        csum += c;
    }
    #pragma unroll
    for (int off = 4; off < 64; off <<= 1) {          // reduce over slots
        acc.x += __shfl_xor(acc.x, off);
        acc.y += __shfl_xor(acc.y, off);
        acc.z += __shfl_xor(acc.z, off);
        acc.w += __shfl_xor(acc.w, off);
        csum  += __shfl_xor(csum, off);
    }
    float4 bb = ((const float4*)b1)[slice * 4 + li];
    float4 ww = ((const float4*)W2)[slice * 4 + li];
    float inv = 1.f / (csum + 1e-16f);
    float t = fmaxf(fmaf(acc.x, inv, bb.x), 0.f) * ww.x
            + fmaxf(fmaf(acc.y, inv, bb.y), 0.f) * ww.y
            + fmaxf(fmaf(acc.z, inv, bb.z), 0.f) * ww.z
            + fmaxf(fmaf(acc.w, inv, bb.w), 0.f) * ww.w;
    t += __shfl_xor(t, 1);
    t += __shfl_xor(t, 2);
    if (lane == 0) atomicAdd(&xw2[d], t);
}

// ================= K5: layer 2 — scalar GAT head, 4 dsts/wave x 16 lanes ==========
__global__ __launch_bounds__(256) void k_layer2(const float* __restrict__ xw2,
                                                const int* __restrict__ row_ptr,
                                                const uint2* __restrict__ pk0,
                                                const float* __restrict__ att_src2,
                                                const float* __restrict__ att_dst2,
                                                const float* __restrict__ b2,
                                                float* __restrict__ out, int N)
{
    int grpi = (blockIdx.x * blockDim.x + threadIdx.x) >> 6;
    int lane = threadIdx.x & 63;
    int sub  = lane >> 4, li = lane & 15;
    int d    = grpi * 4 + sub;
    if (d >= N) return;
    float as2  = att_src2[0];
    float adst = xw2[d] * att_dst2[0];
    float l = 0.f, acc = 0.f;
    int beg = row_ptr[d], end = row_ptr[d + 1];
    for (int j = beg + li; j < end; j += 16) {
        int s = (int)pk0[j].x;
        float xs = xw2[s];
        float p = __expf(lrelu(fmaf(xs, as2, adst)));
        l += p;
        acc = fmaf(p, xs, acc);
    }
    #pragma unroll
    for (int off = 1; off < 16; off <<= 1) {
        l   += __shfl_xor(l, off);
        acc += __shfl_xor(acc, off);
    }
    if (li == 0) out[d] = acc / (l + 1e-16f) + b2[0];
}

extern "C" void kernel_launch(void* const* d_in, const int* in_sizes, int n_in,
                              void* d_out, int out_size, void* d_ws, size_t ws_size,
                              hipStream_t stream)
{
    const float* x        = (const float*)d_in[0];
    const int*   ei       = (const int*)d_in[1];
    const float* W1       = (const float*)d_in[2];
    const float* att_src1 = (const float*)d_in[3];
    const float* att_dst1 = (const float*)d_in[4];
    const float* b1       = (const float*)d_in[5];
    const float* W2       = (const float*)d_in[6];
    const float* att_src2 = (const float*)d_in[7];
    const float* att_dst2 = (const float*)d_in[8];
    const float* b2       = (const float*)d_in[9];
    float* out = (float*)d_out;

    const int N  = in_sizes[0] / 128;
    const int E  = in_sizes[1] / 2;
    const int Et = E + N;
    const int nblk = (N + 2047) / 2048;        // lookback-scan blocks (25 for N=50k)

    char* p = (char*)d_ws;
    auto alloc = [&](size_t bytes) {
        char* r = p;
        p += (bytes + 255) & ~(size_t)255;
        return (void*)r;
    };
    float*    xw      = (float*)alloc((size_t)N * 128 * 4);  // slice-major [8][N][16]
    float*    a_src   = (float*)alloc((size_t)N * 4 * 4);
    float*    a_dst   = (float*)alloc((size_t)N * 4 * 4);
    float*    xw2     = (float*)alloc((size_t)N * 4);
    int*      degpost = (int*)alloc((size_t)(N + nblk + 8) * 4); // deg+post: 1 memset
    int*      deg     = degpost;
    unsigned* post    = (unsigned*)(degpost + N);
    int*      row_ptr = (int*)alloc((size_t)(N + 1) * 4);
    int*      cursor  = (int*)alloc((size_t)N * 4);
    unsigned* inv     = (unsigned*)alloc((size_t)Et * 4);
    uint2*    pk      = (uint2*)alloc((size_t)4 * Et * 8);   // [4][Et] packed {s, e_h}

    hipMemsetAsync(degpost, 0, (size_t)(N + nblk + 8) * 4, stream);

    const int GB = (N + 63) / 64;
    k_gemm_count <<<GB + 256, 256, 0, stream>>>(x, W1, att_src1, att_dst1, ei, E, N, GB,
                                                xw, a_src, a_dst, deg);
    k_scan_lb    <<<nblk,            256, 0, stream>>>(deg, row_ptr, cursor, xw2, post,
                                                       N, nblk);
    k_scatter_pos<<<(Et + 255)/256,  256, 0, stream>>>(ei, E, N, cursor, inv, Et);
    k_build      <<<(Et + 255)/256,  256, 0, stream>>>(ei, E, N, inv, a_src, a_dst,
                                                       pk, Et);
    k_agg        <<<((N + 3)/4)*8,   256, 0, stream>>>(xw, pk, row_ptr, b1, W2, xw2,
                                                       N, Et);
    k_layer2     <<<(N + 15)/16,     256, 0, stream>>>(xw2, row_ptr, pk, att_src2,
                                                       att_dst2, b2, out, N);
}

// Round 14
// 408.981 us; speedup vs baseline: 1.5173x; 1.3080x over previous
//
#include <hip/hip_runtime.h>
#include <hip/hip_bf16.h>
#include <cstdint>
#include <cstddef>
#include <math.h>

#define NEG_SLOPE 0.2f

__device__ __forceinline__ float lrelu(float x) { return x > 0.f ? x : NEG_SLOPE * x; }

// Findings ledger:
//  - k_agg wants SEQUENTIAL per-wave metadata streams (r10/r11/r12: 16 concurrent
//    pk streams/wave thrashed L1/L2, FETCH 70->414 MB; XCD pinning irrelevant).
//  - r13: full-row agg — 2 edge-slots x 32 ch-lanes (float4/lane), xw ROW-major:
//    one dwordx4 moves 2 full 512B rows; edge metadata (csr 4B + eq 16B float4,
//    all heads) read ONCE (vs 8 slice passes re-reading head planes = 105 MB);
//    one wave owns a dst -> direct xw2 store, no atomic, no zeroing.
//  - scatter split (r12) disproven: build's random reads cost more than scattered
//    writes (write-combining absorbs those — r6 vs r7 evidence).
//  - cooperative fusion disproven (r9); on-the-fly e recompute disproven (r7).

// ================= K1: GEMM (blocks < GB) UNION degree-count (blocks >= GB) ======
// xw row-major [N][128]; a_src/a_dst [N][4].
__global__ __launch_bounds__(256) void k_gemm_count(
    const float* __restrict__ x, const float* __restrict__ W1,
    const float* __restrict__ att_src, const float* __restrict__ att_dst,
    const int* __restrict__ ei, int E, int N, int GB,
    float* __restrict__ xw, float* __restrict__ a_src, float* __restrict__ a_dst,
    int* __restrict__ deg)
{
    __shared__ float As[32 * 68];
    __shared__ float Bs[32 * 132];

    if (blockIdx.x >= GB) {                    // ---- count blocks (overlap with GEMM)
        const int Et = E + N;
        const int stride = (gridDim.x - GB) * 256;
        for (int e = (blockIdx.x - GB) * 256 + threadIdx.x; e < Et; e += stride) {
            int d = (e < E) ? ei[(size_t)E + e] : (e - E);
            atomicAdd(&deg[d], 1);
        }
        return;
    }

    const int tid = threadIdx.x;
    const int tx = tid & 31, ty = tid >> 5;
    const int bm = blockIdx.x * 64;
    float acc[8][4] = {};

    for (int k0 = 0; k0 < 128; k0 += 32) {
        #pragma unroll
        for (int t = tid; t < 512; t += 256) {
            int r = t >> 3, q = t & 7;
            int n = bm + r;
            float4 f = make_float4(0.f, 0.f, 0.f, 0.f);
            if (n < N) f = *(const float4*)(x + (size_t)n * 128 + k0 + 4 * q);
            As[(4*q+0)*68 + r] = f.x; As[(4*q+1)*68 + r] = f.y;
            As[(4*q+2)*68 + r] = f.z; As[(4*q+3)*68 + r] = f.w;
        }
        #pragma unroll
        for (int t = tid; t < 1024; t += 256) {
            int c = t >> 3, q = t & 7;
            float4 f = *(const float4*)(W1 + (size_t)c * 128 + k0 + 4 * q);
            Bs[(4*q+0)*132 + c] = f.x; Bs[(4*q+1)*132 + c] = f.y;
            Bs[(4*q+2)*132 + c] = f.z; Bs[(4*q+3)*132 + c] = f.w;
        }
        __syncthreads();
        #pragma unroll 8
        for (int kk = 0; kk < 32; kk++) {
            float4 a0 = *(const float4*)&As[kk * 68 + ty * 8];
            float4 a1 = *(const float4*)&As[kk * 68 + ty * 8 + 4];
            float4 b4 = *(const float4*)&Bs[kk * 132 + tx * 4];
            float a[8] = {a0.x, a0.y, a0.z, a0.w, a1.x, a1.y, a1.z, a1.w};
            float b[4] = {b4.x, b4.y, b4.z, b4.w};
            #pragma unroll
            for (int i = 0; i < 8; i++)
                #pragma unroll
                for (int j = 0; j < 4; j++) acc[i][j] = fmaf(a[i], b[j], acc[i][j]);
        }
        __syncthreads();
    }

    float asv[4], adv[4];
    #pragma unroll
    for (int j = 0; j < 4; j++) { asv[j] = att_src[tx*4+j]; adv[j] = att_dst[tx*4+j]; }
    const int head = tx >> 3;                  // ch = tx*4+j -> head uniform per thread

    #pragma unroll
    for (int i = 0; i < 8; i++) {
        int n = bm + ty * 8 + i;
        float sv = 0.f, dv = 0.f;
        #pragma unroll
        for (int j = 0; j < 4; j++) {
            sv = fmaf(acc[i][j], asv[j], sv);
            dv = fmaf(acc[i][j], adv[j], dv);
        }
        #pragma unroll
        for (int off = 1; off < 8; off <<= 1) {   // 8 lanes of one head
            sv += __shfl_xor(sv, off);
            dv += __shfl_xor(dv, off);
        }
        if (n < N) {
            *(float4*)&xw[(size_t)n * 128 + tx * 4] =
                make_float4(acc[i][0], acc[i][1], acc[i][2], acc[i][3]);
            if ((tx & 7) == 0) {
                a_src[n * 4 + head] = sv;
                a_dst[n * 4 + head] = dv;
            }
        }
    }
}

// ================= K2: single-pass decoupled-lookback scan =======================
__global__ __launch_bounds__(256) void k_scan_lb(const int* __restrict__ deg,
                                                 int* __restrict__ row_ptr,
                                                 int* __restrict__ cursor,
                                                 unsigned* __restrict__ post,
                                                 int N, int nblk)
{
    __shared__ int sw[4];
    __shared__ int s_excl;
    const int b = blockIdx.x, tid = threadIdx.x, wv = tid >> 6, lane = tid & 63;
    const int base = b * 2048 + tid * 8;

    int v[8];
    #pragma unroll
    for (int i = 0; i < 8; i++) v[i] = (base + i < N) ? deg[base + i] : 0;
    int tsum = 0;
    #pragma unroll
    for (int i = 0; i < 8; i++) tsum += v[i];

    int inc = tsum;
    #pragma unroll
    for (int off = 1; off < 64; off <<= 1) {
        int u = __shfl_up(inc, off);
        if (lane >= off) inc += u;
    }
    if (lane == 63) sw[wv] = inc;
    __syncthreads();
    int woff = 0;
    for (int i = 0; i < wv; i++) woff += sw[i];
    const int thr_excl = woff + inc - tsum;
    const int total = sw[0] + sw[1] + sw[2] + sw[3];

    if (tid == 0) {
        int excl = 0;
        if (b == 0) {
            __hip_atomic_store(&post[0], ((unsigned)total << 2) | 2u,
                               __ATOMIC_RELEASE, __HIP_MEMORY_SCOPE_AGENT);
        } else {
            __hip_atomic_store(&post[b], ((unsigned)total << 2) | 1u,
                               __ATOMIC_RELEASE, __HIP_MEMORY_SCOPE_AGENT);
            int j = b - 1;
            long long sum = 0;
            while (true) {
                unsigned pv = __hip_atomic_load(&post[j], __ATOMIC_ACQUIRE,
                                                __HIP_MEMORY_SCOPE_AGENT);
                unsigned st = pv & 3u;
                if (st == 0u) { __builtin_amdgcn_s_sleep(1); continue; }
                sum += (pv >> 2);
                if (st == 2u) break;
                j--;
            }
            excl = (int)sum;
            __hip_atomic_store(&post[b], ((unsigned)(excl + total) << 2) | 2u,
                               __ATOMIC_RELEASE, __HIP_MEMORY_SCOPE_AGENT);
        }
        s_excl = excl;
        if (b == nblk - 1) row_ptr[N] = excl + total;
    }
    __syncthreads();

    int run = s_excl + thr_excl;
    #pragma unroll
    for (int i = 0; i < 8; i++) {
        int idx = base + i;
        if (idx < N) {
            row_ptr[idx] = run;
            cursor[idx]  = run;
            run += v[i];
        }
    }
}

// ================= K3: scatter -> csr_src (4B) + eq (float4: e for 4 heads) =======
__global__ void k_scatter(const int* __restrict__ ei, int E, int N,
                          int* __restrict__ cursor,
                          const float* __restrict__ a_src,
                          const float* __restrict__ a_dst,
                          int* __restrict__ csr_src, float4* __restrict__ eq, int Et)
{
    int e = blockIdx.x * blockDim.x + threadIdx.x;
    if (e >= Et) return;
    int s, d;
    if (e < E) { s = ei[e]; d = ei[(size_t)E + e]; }
    else       { s = d = e - E; }
    int pos = atomicAdd(&cursor[d], 1);
    float4 as4 = ((const float4*)a_src)[s];
    float4 ad4 = ((const float4*)a_dst)[d];
    csr_src[pos] = s;
    eq[pos] = make_float4(__expf(lrelu(as4.x + ad4.x)),
                          __expf(lrelu(as4.y + ad4.y)),
                          __expf(lrelu(as4.z + ad4.z)),
                          __expf(lrelu(as4.w + ad4.w)));
}

// ================= K4: agg — full-row: 2 edge-slots x 32 ch-lanes, 1 dst/wave ====
// Per iteration (2 edges): 1 csr load + 1 eq float4 + 1 xw dwordx4 (full 512B row
// per 32-lane half) + 4 fma. Metadata sequential; direct xw2 store (no atomic).
__global__ __launch_bounds__(256) void k_agg(const float* __restrict__ xw,
                                             const float4* __restrict__ eq,
                                             const int* __restrict__ csr_src,
                                             const int* __restrict__ row_ptr,
                                             const float* __restrict__ b1,
                                             const float* __restrict__ W2,
                                             float* __restrict__ xw2, int N)
{
    const int wv = threadIdx.x >> 6, lane = threadIdx.x & 63;
    const int half = lane >> 5, cl = lane & 31;     // 2 edge-slots x 32 ch-lanes
    const int d = blockIdx.x * 4 + wv;
    if (d >= N) return;
    const int head = cl >> 3;                       // 0..3, uniform per lane
    const int beg = row_ptr[d], end = row_ptr[d + 1];

    float4 acc = make_float4(0.f, 0.f, 0.f, 0.f);
    float csum = 0.f;
    #pragma unroll 2
    for (int k = beg; k < end; k += 2) {
        int j = k + half;
        bool val = (j < end);
        int jj = val ? j : k;                       // k always valid
        int s = csr_src[jj];
        float4 e4 = eq[jj];
        float c = (head & 2) ? ((head & 1) ? e4.w : e4.z)
                             : ((head & 1) ? e4.y : e4.x);
        if (!val) c = 0.f;
        float4 x4 = *(const float4*)(xw + (size_t)s * 128 + cl * 4);
        acc.x = fmaf(c, x4.x, acc.x);
        acc.y = fmaf(c, x4.y, acc.y);
        acc.z = fmaf(c, x4.z, acc.z);
        acc.w = fmaf(c, x4.w, acc.w);
        csum += c;
    }
    // merge the two edge-halves (both hold partials for the same 128 channels)
    acc.x += __shfl_xor(acc.x, 32);
    acc.y += __shfl_xor(acc.y, 32);
    acc.z += __shfl_xor(acc.z, 32);
    acc.w += __shfl_xor(acc.w, 32);
    csum  += __shfl_xor(csum, 32);                  // per-head denominator

    float4 bb = ((const float4*)b1)[cl];
    float4 ww = ((const float4*)W2)[cl];
    float inv = 1.f / (csum + 1e-16f);
    float t = fmaxf(fmaf(acc.x, inv, bb.x), 0.f) * ww.x
            + fmaxf(fmaf(acc.y, inv, bb.y), 0.f) * ww.y
            + fmaxf(fmaf(acc.z, inv, bb.z), 0.f) * ww.z
            + fmaxf(fmaf(acc.w, inv, bb.w), 0.f) * ww.w;
    #pragma unroll
    for (int off = 1; off < 32; off <<= 1) t += __shfl_xor(t, off);
    if (lane == 0) xw2[d] = t;                      // wave owns dst: direct store
}

// ================= K5: layer 2 — scalar GAT head, 4 dsts/wave x 16 lanes ==========
__global__ __launch_bounds__(256) void k_layer2(const float* __restrict__ xw2,
                                                const int* __restrict__ row_ptr,
                                                const int* __restrict__ csr_src,
                                                const float* __restrict__ att_src2,
                                                const float* __restrict__ att_dst2,
                                                const float* __restrict__ b2,
                                                float* __restrict__ out, int N)
{
    int grpi = (blockIdx.x * blockDim.x + threadIdx.x) >> 6;
    int lane = threadIdx.x & 63;
    int sub  = lane >> 4, li = lane & 15;
    int d    = grpi * 4 + sub;
    if (d >= N) return;
    float as2  = att_src2[0];
    float adst = xw2[d] * att_dst2[0];
    float l = 0.f, acc = 0.f;
    int beg = row_ptr[d], end = row_ptr[d + 1];
    for (int j = beg + li; j < end; j += 16) {
        int s = csr_src[j];
        float xs = xw2[s];
        float p = __expf(lrelu(fmaf(xs, as2, adst)));
        l += p;
        acc = fmaf(p, xs, acc);
    }
    #pragma unroll
    for (int off = 1; off < 16; off <<= 1) {
        l   += __shfl_xor(l, off);
        acc += __shfl_xor(acc, off);
    }
    if (li == 0) out[d] = acc / (l + 1e-16f) + b2[0];
}

extern "C" void kernel_launch(void* const* d_in, const int* in_sizes, int n_in,
                              void* d_out, int out_size, void* d_ws, size_t ws_size,
                              hipStream_t stream)
{
    const float* x        = (const float*)d_in[0];
    const int*   ei       = (const int*)d_in[1];
    const float* W1       = (const float*)d_in[2];
    const float* att_src1 = (const float*)d_in[3];
    const float* att_dst1 = (const float*)d_in[4];
    const float* b1       = (const float*)d_in[5];
    const float* W2       = (const float*)d_in[6];
    const float* att_src2 = (const float*)d_in[7];
    const float* att_dst2 = (const float*)d_in[8];
    const float* b2       = (const float*)d_in[9];
    float* out = (float*)d_out;

    const int N  = in_sizes[0] / 128;
    const int E  = in_sizes[1] / 2;
    const int Et = E + N;
    const int nblk = (N + 2047) / 2048;        // lookback-scan blocks (25 for N=50k)

    char* p = (char*)d_ws;
    auto alloc = [&](size_t bytes) {
        char* r = p;
        p += (bytes + 255) & ~(size_t)255;
        return (void*)r;
    };
    float*    xw      = (float*)alloc((size_t)N * 128 * 4);  // row-major [N][128]
    float*    a_src   = (float*)alloc((size_t)N * 4 * 4);
    float*    a_dst   = (float*)alloc((size_t)N * 4 * 4);
    float*    xw2     = (float*)alloc((size_t)N * 4);
    int*      degpost = (int*)alloc((size_t)(N + nblk + 8) * 4); // deg+post: 1 memset
    int*      deg     = degpost;
    unsigned* post    = (unsigned*)(degpost + N);
    int*      row_ptr = (int*)alloc((size_t)(N + 1) * 4);
    int*      cursor  = (int*)alloc((size_t)N * 4);
    int*      csr_src = (int*)alloc((size_t)Et * 4);
    float4*   eq      = (float4*)alloc((size_t)Et * 16);     // e per head, per edge

    (void)hipMemsetAsync(degpost, 0, (size_t)(N + nblk + 8) * 4, stream);

    const int GB = (N + 63) / 64;
    k_gemm_count <<<GB + 256, 256, 0, stream>>>(x, W1, att_src1, att_dst1, ei, E, N, GB,
                                                xw, a_src, a_dst, deg);
    k_scan_lb    <<<nblk,            256, 0, stream>>>(deg, row_ptr, cursor, post,
                                                       N, nblk);
    k_scatter    <<<(Et + 255)/256,  256, 0, stream>>>(ei, E, N, cursor, a_src, a_dst,
                                                       csr_src, eq, Et);
    k_agg        <<<(N + 3)/4,       256, 0, stream>>>(xw, eq, csr_src, row_ptr,
                                                       b1, W2, xw2, N);
    k_layer2     <<<(N + 15)/16,     256, 0, stream>>>(xw2, row_ptr, csr_src, att_src2,
                                                       att_dst2, b2, out, N);
}